// Round 2
// baseline (66574.677 us; speedup 1.0000x reference)
//
#include <hip/hip_runtime.h>
#include <math.h>

// Problem constants
#define B_   64
#define S_   512
#define D_   256
#define H_   512
#define G4   2048           // 4H
#define K0   768            // D + H   (layer 0)
#define K1   1024           // H + H   (layer 1)
#define NWG  256
#define NAH  128            // WGs assigned to layer 0 (group A); rest layer 1 (group B)
#define NTHR 256
#define UPW  4              // hidden units per WG
#define NCOL 16             // 4 gates * UPW columns per WG
#define CK   64             // K-chunk staged through LDS

// ws layout (float/uint indices).
#define OFF_EPO 32          // release epoch (1 uint, own cacheline)
#define OFF_SCL 64          // exp(efw), 256 floats
#define OFF_FLG 512         // 256 arrive flags, padded 16 uints (64B) each
#define OFF_H0  4608        // [2][B][H] layer-0 h, round-parity double buffer
#define OFF_H1  (OFF_H0 + 2*B_*H_)
#define OFF_C0  (OFF_H1 + 2*B_*H_)
#define OFF_C1  (OFF_C0 + B_*H_)
#define OFF_END (OFF_C1 + B_*H_)

__device__ __forceinline__ float sigm(float v) { return 1.0f / (1.0f + expf(-v)); }

// Zero all persistent state (incl. flags/epoch) + precompute exp(efw).
// Stream-ordered before the persistent kernel -> deterministic per replay.
__global__ void lstm_init(const float* __restrict__ efw, float* __restrict__ ws) {
  int stride = gridDim.x * blockDim.x;
  for (int j = blockIdx.x * blockDim.x + threadIdx.x; j < OFF_END; j += stride) {
    float v = 0.0f;
    if (j >= OFF_SCL && j < OFF_SCL + D_) v = expf(efw[j - OFF_SCL]);
    ws[j] = v;
  }
}

// Persistent cooperative kernel. 256 WGs x 256 threads; ~86KB LDS forces
// 1 WG/CU so all 256 WGs are co-resident (grid == CU count).
// Group A (wg<128): layer 0 at time t=r.   Group B: layer 1 at time t=r-1.
// Grid barrier: per-WG padded arrive-flags + WG0-wave0 poll + epoch release
// (no same-address atomic RMWs -- those serialized at ~370ns each = 95us/round).
__launch_bounds__(NTHR, 1)
__global__ void lstm_persist(const float* __restrict__ x,
                             const float* __restrict__ W0,
                             const float* __restrict__ b0,
                             const float* __restrict__ W1,
                             const float* __restrict__ b1,
                             float* __restrict__ out,
                             float* __restrict__ ws)
{
  __shared__ float wW[K1][NCOL];        // 64 KB  weight slice [k][col], col = gate*4+uu
  __shared__ float aT[CK][B_ + 1];      // 16.6KB A-chunk, k-major, +1 pad -> 2-way banks
  __shared__ float zB[4][B_][UPW + 1];  // 5.1 KB gate exchange, +1 pad
  __shared__ float scl[D_];             // 1 KB   exp(efw)

  const int  wg  = blockIdx.x;
  const int  tid = threadIdx.x;
  const bool isA = (wg < NAH);
  const int  u0  = (isA ? wg : wg - NAH) * UPW;
  const int  K   = isA ? K0 : K1;
  const int  nch = K / CK;              // 12 (A) / 16 (B)

  float* h0 = ws + OFF_H0;              // [2][B_][H_]
  float* h1 = ws + OFF_H1;
  float* cs = ws + (isA ? OFF_C0 : OFF_C1);   // [B_][H_], WG-exclusive units
  unsigned* epo = (unsigned*)ws + OFF_EPO;
  unsigned* flg = (unsigned*)ws + OFF_FLG;    // flg[wg*16]

  // Stage this WG's weight slice into LDS (once).
  {
    const float* W = isA ? W0 : W1;
    for (int i = tid; i < K * NCOL; i += NTHR) {
      int k = i >> 4, cl = i & 15;
      int g = cl >> 2, uu = cl & 3;
      wW[k][cl] = W[(size_t)k * G4 + g * H_ + u0 + uu];
    }
  }
  for (int i = tid; i < D_; i += NTHR) scl[i] = ws[OFF_SCL + i];

  const int bb = tid & 63;              // batch row for GEMM phase
  const int cg = tid >> 6;              // gate index (cols cg*4 .. cg*4+3)
  float bias[4];
  {
    const float* bv = isA ? b0 : b1;
#pragma unroll
    for (int j = 0; j < 4; ++j) bias[j] = bv[cg * H_ + u0 + j];
  }
  const int b2 = tid & 63;              // batch row for update phase
  const int uu = tid >> 6;              // unit sub-index for update phase

  for (int r = 0; r <= S_; ++r) {
    const int  p   = r & 1;
    const bool act = isA ? (r < S_) : (r >= 1);
    if (act) {
      const int t = isA ? r : r - 1;
      const float* hp0 = h0 + (size_t)(p ^ 1) * B_ * H_;
      const float* hp1 = h1 + (size_t)(p ^ 1) * B_ * H_;
      float a0 = 0.f, a1 = 0.f, a2 = 0.f, a3 = 0.f;

      for (int c = 0; c < nch; ++c) {
        __syncthreads();                // protect aT reuse
        // Stage chunk: 64 k x 64 rows, transposed into aT[k][row].
#pragma unroll
        for (int i = 0; i < 4; ++i) {
          int idx = tid + NTHR * i;     // 0..1023
          int row = idx >> 4;           // 0..63
          int kk  = (idx & 15) << 2;    // 0,4,..,60
          int gk  = c * CK + kk;
          float4 v;
          if (isA) {
            if (gk < D_) {              // x part, scaled by exp(efw)
              v = *(const float4*)(x + (size_t)(row * S_ + t) * D_ + gk);
              float4 sc = *(const float4*)(&scl[gk]);
              v.x *= sc.x; v.y *= sc.y; v.z *= sc.z; v.w *= sc.w;
            } else {                    // h0_prev part
              v = *(const float4*)(hp0 + (size_t)row * H_ + (gk - D_));
            }
          } else {
            if (gk < H_) v = *(const float4*)(hp0 + (size_t)row * H_ + gk);        // h0[t]
            else         v = *(const float4*)(hp1 + (size_t)row * H_ + (gk - H_)); // h1[t-1]
          }
          aT[kk + 0][row] = v.x; aT[kk + 1][row] = v.y;
          aT[kk + 2][row] = v.z; aT[kk + 3][row] = v.w;
        }
        __syncthreads();
        // Accumulate: thread (bb, cg) -> 4 gate columns of gate cg, row bb.
        const float* wrow = &wW[c * CK][0];
#pragma unroll
        for (int kk = 0; kk < CK; ++kk) {
          float  a = aT[kk][bb];                                  // 2-way banks (free)
          float4 w = *(const float4*)(wrow + kk * NCOL + cg * 4); // wave-uniform broadcast
          a0 += a * w.x; a1 += a * w.y; a2 += a * w.z; a3 += a * w.w;
        }
      }

      // Exchange gates: thread (bb,cg) holds gate cg for units u0+0..3.
      zB[cg][bb][0] = a0 + bias[0];
      zB[cg][bb][1] = a1 + bias[1];
      zB[cg][bb][2] = a2 + bias[2];
      zB[cg][bb][3] = a3 + bias[3];
      __syncthreads();

      // Pointwise cell update: thread (b2, uu) owns (row b2, unit u0+uu).
      {
        float zi = zB[0][b2][uu], zf = zB[1][b2][uu];
        float zg = zB[2][b2][uu], zo = zB[3][b2][uu];
        int   ui = u0 + uu;
        float c_ = cs[b2 * H_ + ui];
        float i_ = sigm(zi);
        float f_ = sigm(zf + c_) * 0.9f;   // decayed forget gate (DECAY=0.1)
        float g_ = tanhf(zg);
        float o_ = sigm(zo);
        float cn = f_ * c_ + i_ * g_;
        float hn = o_ * tanhf(cn);
        cs[b2 * H_ + ui] = cn;
        float* hw = (isA ? h0 : h1) + (size_t)p * B_ * H_ + b2 * H_ + ui;
        *hw = hn;
        if (!isA) out[((size_t)b2 * S_ + t) * H_ + ui] = hn;
      }
    }

    // ---- grid barrier: padded flags + single poller + epoch release ----
    if (r < S_) {
      __syncthreads();                  // all waves of this WG done with round r
      const unsigned tgt = (unsigned)(r + 1);
      if (tid == 0) {
        __threadfence();                // agent-scope release of h/c/out stores
        __hip_atomic_store(flg + (size_t)wg * 16, tgt, __ATOMIC_RELEASE,
                           __HIP_MEMORY_SCOPE_AGENT);
      }
      if (wg == 0 && tid < 64) {        // wave 0 of WG 0: poll all 256 flags
        for (;;) {
          unsigned m0 = __hip_atomic_load(flg + (size_t)(tid       ) * 16,
                                          __ATOMIC_ACQUIRE, __HIP_MEMORY_SCOPE_AGENT);
          unsigned m1 = __hip_atomic_load(flg + (size_t)(tid +  64) * 16,
                                          __ATOMIC_ACQUIRE, __HIP_MEMORY_SCOPE_AGENT);
          unsigned m2 = __hip_atomic_load(flg + (size_t)(tid + 128) * 16,
                                          __ATOMIC_ACQUIRE, __HIP_MEMORY_SCOPE_AGENT);
          unsigned m3 = __hip_atomic_load(flg + (size_t)(tid + 192) * 16,
                                          __ATOMIC_ACQUIRE, __HIP_MEMORY_SCOPE_AGENT);
          if (__all(m0 >= tgt && m1 >= tgt && m2 >= tgt && m3 >= tgt)) break;
          __builtin_amdgcn_s_sleep(2);
        }
        if (tid == 0)
          __hip_atomic_store(epo, tgt, __ATOMIC_RELEASE, __HIP_MEMORY_SCOPE_AGENT);
      }
      while (__hip_atomic_load(epo, __ATOMIC_ACQUIRE, __HIP_MEMORY_SCOPE_AGENT) < tgt)
        __builtin_amdgcn_s_sleep(2);
    }
  }
}

extern "C" void kernel_launch(void* const* d_in, const int* in_sizes, int n_in,
                              void* d_out, int out_size, void* d_ws, size_t ws_size,
                              hipStream_t stream) {
  const float* x   = (const float*)d_in[0];
  const float* W0  = (const float*)d_in[1];
  const float* b0  = (const float*)d_in[2];
  const float* W1  = (const float*)d_in[3];
  const float* b1  = (const float*)d_in[4];
  const float* efw = (const float*)d_in[5];
  float* out = (float*)d_out;
  float* ws  = (float*)d_ws;

  if (ws_size < (size_t)OFF_END * sizeof(float)) return;  // need ~0.8 MB scratch

  lstm_init<<<256, 256, 0, stream>>>(efw, ws);
  lstm_persist<<<NWG, NTHR, 0, stream>>>(x, W0, b0, W1, b1, out, ws);
}

// Round 3
// 25698.727 us; speedup vs baseline: 2.5906x; 2.5906x over previous
//
#include <hip/hip_runtime.h>
#include <math.h>

// Problem constants
#define B_   64
#define S_   512
#define D_   256
#define H_   512
#define G4   2048           // 4H
#define K0   768            // D + H   (layer 0)
#define K1   1024           // H + H   (layer 1)
#define NWG  256
#define NAH  128            // WGs assigned to layer 0 (group A); rest layer 1 (group B)
#define NTHR 256
#define UPW  4              // hidden units per WG
#define NCOL 16             // 4 gates * UPW columns per WG
#define CK   64             // K-chunk staged through LDS

// ws layout (float/uint indices).
#define OFF_EPO 32          // release epoch (1 uint, own cacheline)
#define OFF_SCL 64          // exp(efw), 256 floats
#define OFF_FLG 512         // 256 arrive flags, padded 16 uints (64B) each
#define OFF_H0  4608        // [2][B][H] layer-0 h, round-parity double buffer
#define OFF_H1  (OFF_H0 + 2*B_*H_)
#define OFF_C0  (OFF_H1 + 2*B_*H_)
#define OFF_C1  (OFF_C0 + B_*H_)
#define OFF_END (OFF_C1 + B_*H_)

__device__ __forceinline__ float sigm(float v) { return 1.0f / (1.0f + expf(-v)); }

// Zero all persistent state (incl. flags/epoch) + precompute exp(efw).
// Stream-ordered before the persistent kernel -> deterministic per replay.
// (Kernel-end release makes these zeros visible to lstm_persist's sc1 loads.)
__global__ void lstm_init(const float* __restrict__ efw, float* __restrict__ ws) {
  int stride = gridDim.x * blockDim.x;
  for (int j = blockIdx.x * blockDim.x + threadIdx.x; j < OFF_END; j += stride) {
    float v = 0.0f;
    if (j >= OFF_SCL && j < OFF_SCL + D_) v = expf(efw[j - OFF_SCL]);
    ws[j] = v;
  }
}

// Persistent cooperative kernel. 256 WGs x 256 threads; ~86KB LDS forces
// 1 WG/CU so all 256 WGs are co-resident (grid == CU count).
// Group A (wg<128): layer 0 at time t=r.   Group B: layer 1 at time t=r-1.
//
// Grid barrier (R3): RELAXED spin loads (plain sc1 loads, no buffer_inv per
// iteration) + exactly ONE release fence (buffer_wbl2) per WG on arrive and
// ONE acquire fence (buffer_inv) per WG on depart. R1/R2 spun with ACQUIRE
// loads from all 1024 waves -> per-iteration L2-invalidate storm ~100us/round.
__launch_bounds__(NTHR, 1)
__global__ void lstm_persist(const float* __restrict__ x,
                             const float* __restrict__ W0,
                             const float* __restrict__ b0,
                             const float* __restrict__ W1,
                             const float* __restrict__ b1,
                             float* __restrict__ out,
                             float* __restrict__ ws)
{
  __shared__ float wW[K1][NCOL];        // 64 KB  weight slice [k][col], col = gate*4+uu
  __shared__ float aT[CK][B_ + 1];      // 16.6KB A-chunk, k-major, +1 pad -> 2-way banks
  __shared__ float zB[4][B_][UPW + 1];  // 5.1 KB gate exchange, +1 pad
  __shared__ float scl[D_];             // 1 KB   exp(efw)

  const int  wg  = blockIdx.x;
  const int  tid = threadIdx.x;
  const bool isA = (wg < NAH);
  const int  u0  = (isA ? wg : wg - NAH) * UPW;
  const int  K   = isA ? K0 : K1;
  const int  nch = K / CK;              // 12 (A) / 16 (B)

  float* h0 = ws + OFF_H0;              // [2][B_][H_]
  float* h1 = ws + OFF_H1;
  float* cs = ws + (isA ? OFF_C0 : OFF_C1);   // [B_][H_], WG-exclusive units
  unsigned* epo = (unsigned*)ws + OFF_EPO;
  unsigned* flg = (unsigned*)ws + OFF_FLG;    // flg[wg*16]

  // Stage this WG's weight slice into LDS (once).
  {
    const float* W = isA ? W0 : W1;
    for (int i = tid; i < K * NCOL; i += NTHR) {
      int k = i >> 4, cl = i & 15;
      int g = cl >> 2, uu = cl & 3;
      wW[k][cl] = W[(size_t)k * G4 + g * H_ + u0 + uu];
    }
  }
  for (int i = tid; i < D_; i += NTHR) scl[i] = ws[OFF_SCL + i];

  const int bb = tid & 63;              // batch row for GEMM phase
  const int cg = tid >> 6;              // gate index (cols cg*4 .. cg*4+3)
  float bias[4];
  {
    const float* bv = isA ? b0 : b1;
#pragma unroll
    for (int j = 0; j < 4; ++j) bias[j] = bv[cg * H_ + u0 + j];
  }
  const int b2 = tid & 63;              // batch row for update phase
  const int uu = tid >> 6;              // unit sub-index for update phase

  for (int r = 0; r <= S_; ++r) {
    const int  p   = r & 1;
    const bool act = isA ? (r < S_) : (r >= 1);
    if (act) {
      const int t = isA ? r : r - 1;
      const float* hp0 = h0 + (size_t)(p ^ 1) * B_ * H_;
      const float* hp1 = h1 + (size_t)(p ^ 1) * B_ * H_;
      float a0 = 0.f, a1 = 0.f, a2 = 0.f, a3 = 0.f;

      for (int c = 0; c < nch; ++c) {
        __syncthreads();                // protect aT reuse
        // Stage chunk: 64 k x 64 rows, transposed into aT[k][row].
#pragma unroll
        for (int i = 0; i < 4; ++i) {
          int idx = tid + NTHR * i;     // 0..1023
          int row = idx >> 4;           // 0..63
          int kk  = (idx & 15) << 2;    // 0,4,..,60
          int gk  = c * CK + kk;
          float4 v;
          if (isA) {
            if (gk < D_) {              // x part, scaled by exp(efw)
              v = *(const float4*)(x + (size_t)(row * S_ + t) * D_ + gk);
              float4 sc = *(const float4*)(&scl[gk]);
              v.x *= sc.x; v.y *= sc.y; v.z *= sc.z; v.w *= sc.w;
            } else {                    // h0_prev part
              v = *(const float4*)(hp0 + (size_t)row * H_ + (gk - D_));
            }
          } else {
            if (gk < H_) v = *(const float4*)(hp0 + (size_t)row * H_ + gk);        // h0[t]
            else         v = *(const float4*)(hp1 + (size_t)row * H_ + (gk - H_)); // h1[t-1]
          }
          aT[kk + 0][row] = v.x; aT[kk + 1][row] = v.y;
          aT[kk + 2][row] = v.z; aT[kk + 3][row] = v.w;
        }
        __syncthreads();
        // Accumulate: thread (bb, cg) -> 4 gate columns of gate cg, row bb.
        const float* wrow = &wW[c * CK][0];
#pragma unroll
        for (int kk = 0; kk < CK; ++kk) {
          float  a = aT[kk][bb];                                  // 2-way banks (free)
          float4 w = *(const float4*)(wrow + kk * NCOL + cg * 4); // wave-uniform broadcast
          a0 += a * w.x; a1 += a * w.y; a2 += a * w.z; a3 += a * w.w;
        }
      }

      // Exchange gates: thread (bb,cg) holds gate cg for units u0+0..3.
      zB[cg][bb][0] = a0 + bias[0];
      zB[cg][bb][1] = a1 + bias[1];
      zB[cg][bb][2] = a2 + bias[2];
      zB[cg][bb][3] = a3 + bias[3];
      __syncthreads();

      // Pointwise cell update: thread (b2, uu) owns (row b2, unit u0+uu).
      {
        float zi = zB[0][b2][uu], zf = zB[1][b2][uu];
        float zg = zB[2][b2][uu], zo = zB[3][b2][uu];
        int   ui = u0 + uu;
        float c_ = cs[b2 * H_ + ui];
        float i_ = sigm(zi);
        float f_ = sigm(zf + c_) * 0.9f;   // decayed forget gate (DECAY=0.1)
        float g_ = tanhf(zg);
        float o_ = sigm(zo);
        float cn = f_ * c_ + i_ * g_;
        float hn = o_ * tanhf(cn);
        cs[b2 * H_ + ui] = cn;
        float* hw = (isA ? h0 : h1) + (size_t)p * B_ * H_ + b2 * H_ + ui;
        *hw = hn;
        if (!isA) out[((size_t)b2 * S_ + t) * H_ + ui] = hn;
      }
    }

    // ---- grid barrier: relaxed spins, one wb + one inv per WG per round ----
    if (r < S_) {
      __syncthreads();                  // all waves' stores complete (to local L2)
      const unsigned tgt = (unsigned)(r + 1);
      if (tid == 0) {
        // ONE agent release fence: waitcnt + buffer_wbl2 (pushes h/c to IF$).
        __builtin_amdgcn_fence(__ATOMIC_RELEASE, "agent");
        __hip_atomic_store(flg + (size_t)wg * 16, tgt, __ATOMIC_RELAXED,
                           __HIP_MEMORY_SCOPE_AGENT);
      }
      if (wg == 0 && tid < 64) {        // WG0 wave0: poll all 256 flags, RELAXED
        for (;;) {
          unsigned m0 = __hip_atomic_load(flg + (size_t)(tid       ) * 16,
                                          __ATOMIC_RELAXED, __HIP_MEMORY_SCOPE_AGENT);
          unsigned m1 = __hip_atomic_load(flg + (size_t)(tid +  64) * 16,
                                          __ATOMIC_RELAXED, __HIP_MEMORY_SCOPE_AGENT);
          unsigned m2 = __hip_atomic_load(flg + (size_t)(tid + 128) * 16,
                                          __ATOMIC_RELAXED, __HIP_MEMORY_SCOPE_AGENT);
          unsigned m3 = __hip_atomic_load(flg + (size_t)(tid + 192) * 16,
                                          __ATOMIC_RELAXED, __HIP_MEMORY_SCOPE_AGENT);
          if (__all(m0 >= tgt && m1 >= tgt && m2 >= tgt && m3 >= tgt)) break;
          __builtin_amdgcn_s_sleep(2);
        }
        if (tid == 0)                   // store is value-dependent on the loads
          __hip_atomic_store(epo, tgt, __ATOMIC_RELAXED, __HIP_MEMORY_SCOPE_AGENT);
      }
      if (tid < 64) {                   // wave 0 spins; waves 1-3 park at barrier
        while (__hip_atomic_load(epo, __ATOMIC_RELAXED, __HIP_MEMORY_SCOPE_AGENT) < tgt)
          __builtin_amdgcn_s_sleep(1);
        // ONE agent acquire fence: buffer_inv (drops stale NC lines; L1/L2 are
        // physically shared, so this covers waves 1-3's post-barrier loads too).
        __builtin_amdgcn_fence(__ATOMIC_ACQUIRE, "agent");
      }
      __syncthreads();
    }
  }
}

extern "C" void kernel_launch(void* const* d_in, const int* in_sizes, int n_in,
                              void* d_out, int out_size, void* d_ws, size_t ws_size,
                              hipStream_t stream) {
  const float* x   = (const float*)d_in[0];
  const float* W0  = (const float*)d_in[1];
  const float* b0  = (const float*)d_in[2];
  const float* W1  = (const float*)d_in[3];
  const float* b1  = (const float*)d_in[4];
  const float* efw = (const float*)d_in[5];
  float* out = (float*)d_out;
  float* ws  = (float*)d_ws;

  if (ws_size < (size_t)OFF_END * sizeof(float)) return;  // need ~0.8 MB scratch

  lstm_init<<<256, 256, 0, stream>>>(efw, ws);
  lstm_persist<<<NWG, NTHR, 0, stream>>>(x, W0, b0, W1, b1, out, ws);
}

// Round 4
// 24704.877 us; speedup vs baseline: 2.6948x; 1.0402x over previous
//
#include <hip/hip_runtime.h>
#include <math.h>

// Problem constants
#define B_   64
#define S_   512
#define D_   256
#define H_   512
#define G4   2048           // 4H
#define K0   768            // D + H   (layer 0)
#define K1   1024           // H + H   (layer 1)
#define NWG  256
#define NAH  128            // WGs 0-127: layer 0 (group A); 128-255: layer 1 (group B)
#define NTHR 256
#define CK   64             // K-chunk staged through LDS

// ws layout (float/uint indices)
#define OFF_EPO 32          // 8 epoch replicas, stride 16 uints -> [32,160)
#define OFF_SCL 192         // exp(efw), 256 floats -> [192,448)
#define OFF_FLG 512         // 256 arrive flags, 16-uint (64B) padded -> [512,4608)
#define OFF_H0  4608        // [2][B][H] layer-0 h (round-parity double buffer)
#define OFF_H1  (OFF_H0 + 2*B_*H_)
#define OFF_C0  (OFF_H1 + 2*B_*H_)
#define OFF_C1  (OFF_C0 + B_*H_)
#define OFF_END (OFF_C1 + B_*H_)

__device__ __forceinline__ float sigm(float v) { return 1.0f / (1.0f + expf(-v)); }

// Device-scope (sc1) relaxed atomics: per-access coherence through IF$,
// NO bulk wbl2/inv cache-maintenance ops (those were ~45us/round in R3).
#define ALD(p)   __hip_atomic_load((p), __ATOMIC_RELAXED, __HIP_MEMORY_SCOPE_AGENT)
#define AST(p,v) __hip_atomic_store((p), (v), __ATOMIC_RELAXED, __HIP_MEMORY_SCOPE_AGENT)

// Zero all persistent state + precompute exp(efw). Kernel-end implicit
// writeback publishes zeros; kernel-start invalidate on lstm_persist makes
// them visible. Runs stream-ordered each call -> deterministic per replay.
__global__ void lstm_init(const float* __restrict__ efw, float* __restrict__ ws) {
  int stride = gridDim.x * blockDim.x;
  for (int j = blockIdx.x * blockDim.x + threadIdx.x; j < OFF_END; j += stride) {
    float v = 0.0f;
    if (j >= OFF_SCL && j < OFF_SCL + D_) v = expf(efw[j - OFF_SCL]);
    ws[j] = v;
  }
}

// Persistent kernel: 256 WGs x 256 threads, 102KB LDS -> 1 WG/CU, all
// co-resident. Group A: layer 0 at t=r; group B: layer 1 at t=r-1.
// Coherence: h-state r/w via sc1 atomics only; c/out/x/W plain (CU-local or
// read-only). Barrier: arrive flags + WG0 poll + replicated epoch, all
// relaxed sc1, ZERO fences in the loop.
__launch_bounds__(NTHR, 1)
__global__ void lstm_persist(const float* __restrict__ x,
                             const float* __restrict__ W0,
                             const float* __restrict__ b0,
                             const float* __restrict__ W1,
                             const float* __restrict__ b1,
                             float* __restrict__ out,
                             float* __restrict__ ws)
{
  __shared__ float wW[K1][16];      // 64 KB   weight slice [k][col], col=g*4+uu
  __shared__ float aT[CK][68];      // 17.4 KB A-chunk [k][row], row-contig, pad 68
  __shared__ float pR[4][B_][20];   // 20.5 KB per-wave partial sums [w][row][col]
  __shared__ float scl[D_];         // 1 KB    exp(efw)
  // total 104448 B > 80KB -> exactly 1 WG/CU

  const int  wg  = blockIdx.x;
  const int  tid = threadIdx.x;
  const bool isA = (wg < NAH);
  const int  u0  = (isA ? wg : wg - NAH) * 4;
  const int  K   = isA ? K0 : K1;
  const int  nch = K / CK;          // 12 (A) / 16 (B)

  float* h0 = ws + OFF_H0;
  float* h1 = ws + OFF_H1;
  float* cs = ws + (isA ? OFF_C0 : OFF_C1);
  unsigned* epo = (unsigned*)ws + OFF_EPO;
  unsigned* flg = (unsigned*)ws + OFF_FLG;

  // One-time: stage weight slice (plain, read-only) into LDS.
  {
    const float* W = isA ? W0 : W1;
    for (int i = tid; i < K * 16; i += NTHR) {
      int k = i >> 4, cl = i & 15, g = cl >> 2, u2 = cl & 3;
      wW[k][cl] = W[(size_t)k * G4 + g * H_ + u0 + u2];
    }
  }
  for (int i = tid; i < D_; i += NTHR) scl[i] = ws[OFF_SCL + i];

  // GEMM-phase roles: thread = (row-group rq, col-group cq, k-phase wave wv_)
  const int rq  = tid & 15;         // rows 4rq..4rq+3
  const int cq  = (tid >> 4) & 3;   // cols 4cq..4cq+3
  const int wv_ = tid >> 6;         // wave: k in [c*64+16*wv_, +16)
  // Update-phase roles: thread = (batch row_r, unit uu)
  const int row_r = tid & 63;
  const int uu    = tid >> 6;
  float bias[4];
  {
    const float* bv = isA ? b0 : b1;
#pragma unroll
    for (int g = 0; g < 4; ++g) bias[g] = bv[g * H_ + u0 + uu];
  }

  __syncthreads();                  // scl/wW ready (chunk-0 prefetch reads scl)

  // Stage chunk c of A into registers (16 floats). h-sourced -> sc1 loads.
  float rg[16];
  auto stage_load = [&](int c, const float* hp0, const float* hp1, int t) {
#pragma unroll
    for (int i = 0; i < 4; ++i) {
      int s   = tid + NTHR * i;     // 0..1023
      int row = s >> 4;
      int gk  = c * CK + ((s & 15) << 2);
      if (isA) {
        if (gk < D_) {              // x part (read-only, plain), scaled
          float4 v  = *(const float4*)(x + ((size_t)row * S_ + t) * D_ + gk);
          float4 sc = *(const float4*)&scl[gk];
          rg[4*i+0] = v.x * sc.x; rg[4*i+1] = v.y * sc.y;
          rg[4*i+2] = v.z * sc.z; rg[4*i+3] = v.w * sc.w;
        } else {                    // h0_prev: cross-WG -> sc1
          const float* src = hp0 + (size_t)row * H_ + (gk - D_);
          rg[4*i+0] = ALD(src+0); rg[4*i+1] = ALD(src+1);
          rg[4*i+2] = ALD(src+2); rg[4*i+3] = ALD(src+3);
        }
      } else {
        const float* src = (gk < H_) ? hp0 + (size_t)row * H_ + gk
                                     : hp1 + (size_t)row * H_ + (gk - H_);
        rg[4*i+0] = ALD(src+0); rg[4*i+1] = ALD(src+1);
        rg[4*i+2] = ALD(src+2); rg[4*i+3] = ALD(src+3);
      }
    }
  };

  for (int r = 0; r <= S_; ++r) {
    const int  p   = r & 1;
    const bool act = isA ? (r < S_) : (r >= 1);
    if (act) {
      const int t = isA ? r : r - 1;
      const float* hp0 = h0 + (size_t)(p ^ 1) * B_ * H_;
      const float* hp1 = h1 + (size_t)(p ^ 1) * B_ * H_;
      float acc[4][4] = {{0.f,0.f,0.f,0.f},{0.f,0.f,0.f,0.f},
                         {0.f,0.f,0.f,0.f},{0.f,0.f,0.f,0.f}};
      stage_load(0, hp0, hp1, t);

      for (int c = 0; c < nch; ++c) {
        __syncthreads();            // aT free (prev chunk's compute done)
        // regs -> aT (transpose to [k][row])
#pragma unroll
        for (int i = 0; i < 4; ++i) {
          int s = tid + NTHR * i;
          int row = s >> 4, kk = (s & 15) << 2;
          aT[kk+0][row] = rg[4*i+0]; aT[kk+1][row] = rg[4*i+1];
          aT[kk+2][row] = rg[4*i+2]; aT[kk+3][row] = rg[4*i+3];
        }
        if (c + 1 < nch) stage_load(c + 1, hp0, hp1, t);  // overlap w/ compute
        __syncthreads();            // aT ready
        const int kb = wv_ * 16;
#pragma unroll
        for (int kk = 0; kk < 16; ++kk) {
          float4 a  = *(const float4*)&aT[kb + kk][rq << 2];
          float4 wv = *(const float4*)&wW[c * CK + kb + kk][cq << 2];
          acc[0][0] += a.x*wv.x; acc[0][1] += a.x*wv.y; acc[0][2] += a.x*wv.z; acc[0][3] += a.x*wv.w;
          acc[1][0] += a.y*wv.x; acc[1][1] += a.y*wv.y; acc[1][2] += a.y*wv.z; acc[1][3] += a.y*wv.w;
          acc[2][0] += a.z*wv.x; acc[2][1] += a.z*wv.y; acc[2][2] += a.z*wv.z; acc[2][3] += a.z*wv.w;
          acc[3][0] += a.w*wv.x; acc[3][1] += a.w*wv.y; acc[3][2] += a.w*wv.z; acc[3][3] += a.w*wv.w;
        }
      }

      // Per-wave partials -> LDS
#pragma unroll
      for (int j = 0; j < 4; ++j) {
        pR[wv_][(rq<<2)+j][(cq<<2)+0] = acc[j][0];
        pR[wv_][(rq<<2)+j][(cq<<2)+1] = acc[j][1];
        pR[wv_][(rq<<2)+j][(cq<<2)+2] = acc[j][2];
        pR[wv_][(rq<<2)+j][(cq<<2)+3] = acc[j][3];
      }
      __syncthreads();

      // Reduce across waves + cell update: thread (row_r, unit uu)
      float z[4];
#pragma unroll
      for (int g = 0; g < 4; ++g) {
        int cl = (g << 2) + uu;
        z[g] = pR[0][row_r][cl] + pR[1][row_r][cl]
             + pR[2][row_r][cl] + pR[3][row_r][cl] + bias[g];
      }
      const int ui = u0 + uu;
      float c_ = cs[(size_t)row_r * H_ + ui];      // CU-local, plain
      float i_ = sigm(z[0]);
      float f_ = sigm(z[1] + c_) * 0.9f;           // decayed forget (DECAY=0.1)
      float g_ = tanhf(z[2]);
      float o_ = sigm(z[3]);
      float cn = f_ * c_ + i_ * g_;
      float hn = o_ * tanhf(cn);
      cs[(size_t)row_r * H_ + ui] = cn;
      float* hw = (isA ? h0 : h1) + (size_t)p * B_ * H_ + (size_t)row_r * H_ + ui;
      AST(hw, hn);                                  // sc1 write-through
      if (!isA) out[((size_t)row_r * S_ + t) * H_ + ui] = hn;  // plain
    }

    // ---- grid barrier: all relaxed sc1, zero fences ----
    if (r < S_) {
      __syncthreads();              // drains vmcnt(0): h-stores retired at IF$
      const unsigned tgt = (unsigned)(r + 1);
      if (tid == 0) AST(flg + (size_t)wg * 16, tgt);
      if (wg == 0 && tid < 64) {    // dedicated poll wave
        for (;;) {
          unsigned m0 = ALD(flg + (size_t)(tid       ) * 16);
          unsigned m1 = ALD(flg + (size_t)(tid +  64) * 16);
          unsigned m2 = ALD(flg + (size_t)(tid + 128) * 16);
          unsigned m3 = ALD(flg + (size_t)(tid + 192) * 16);
          if (__all(m0 >= tgt && m1 >= tgt && m2 >= tgt && m3 >= tgt)) break;
        }
        if (tid == 0) {
#pragma unroll
          for (int kq = 0; kq < 8; ++kq) AST(epo + (size_t)kq * 16, tgt);
        }
      }
      if (tid < 64) {               // wave 0 spins on this WG's epoch replica
        while (ALD(epo + (size_t)(wg & 7) * 16) < tgt)
          __builtin_amdgcn_s_sleep(4);
      }
      __syncthreads();
    }
  }
}

extern "C" void kernel_launch(void* const* d_in, const int* in_sizes, int n_in,
                              void* d_out, int out_size, void* d_ws, size_t ws_size,
                              hipStream_t stream) {
  const float* x   = (const float*)d_in[0];
  const float* W0  = (const float*)d_in[1];
  const float* b0  = (const float*)d_in[2];
  const float* W1  = (const float*)d_in[3];
  const float* b1  = (const float*)d_in[4];
  const float* efw = (const float*)d_in[5];
  float* out = (float*)d_out;
  float* ws  = (float*)d_ws;

  if (ws_size < (size_t)OFF_END * sizeof(float)) return;  // ~0.8 MB scratch

  lstm_init<<<256, 256, 0, stream>>>(efw, ws);
  lstm_persist<<<NWG, NTHR, 0, stream>>>(x, W0, b0, W1, b1, out, ws);
}

// Round 7
// 9371.744 us; speedup vs baseline: 7.1038x; 2.6361x over previous
//
#include <hip/hip_runtime.h>
#include <math.h>

// Problem constants
#define B_   64
#define S_   512
#define D_   256
#define H_   512
#define G4   2048           // 4H
#define K0   768            // D + H   (layer 0)
#define K1   1024           // H + H   (layer 1)
#define NWG  256
#define NAH  128            // WGs 0-127: layer 0 (A); 128-255: layer 1 (B)
#define NTHR 256
#define CK   64             // K-chunk staged through LDS
#define BH   32768          // B_*H_
#define NROT 4              // xbuf rotation depth (L0 reuse-distance >= 4 rounds)

// ws layout (float/uint indices)
#define OFF_EPO  32         // global epoch replicas 8x16
#define OFF_SCL  192        // exp(efw), 256 floats
#define OFF_FLG  512        // 256 global arrive flags x16 -> [512,4608)
#define OFF_TKT  4608       // per-XCD tickets 8x16
#define OFF_XCN  4736       // per-XCD event counters 8x16
#define OFF_H0   5120       // [2][B][H] layer-0 h (parity double buffer)
#define OFF_H1   (OFF_H0 + 2*BH)
#define OFF_C0   (OFF_H1 + 2*BH)
#define OFF_C1   (OFF_C0 + BH)
#define OFF_ZEND (OFF_C1 + BH)          // = 201728, init zeroes up to here
#define OFF_XBUF OFF_ZEND               // per-XCD staging: [8][NROT][2*BH]
#define XBUF_SZ  (8 * NROT * 2 * BH)
#define OFF_END  (OFF_XBUF + XBUF_SZ)   // ~9.2 MB

__device__ __forceinline__ float sigm(float v) { return 1.0f / (1.0f + expf(-v)); }

// sc1 (IF$-point) relaxed atomics -- cross-XCD safe (R4-proven).
#define ALD(p)   __hip_atomic_load((p), __ATOMIC_RELAXED, __HIP_MEMORY_SCOPE_AGENT)
#define AST(p,v) __hip_atomic_store((p), (v), __ATOMIC_RELAXED, __HIP_MEMORY_SCOPE_AGENT)

// Intra-XCD primitives: atomic RMWs execute at the local L2 (L0 has no atomic
// path -> can never be served stale from L0, unlike ANY load flavor: sc0 loads
// are L0-cacheable, which deadlocked R5/R6 spins). No sc1 -> stays at own L2.
__device__ __forceinline__ void xadd_noret(unsigned* p, unsigned v) {
  asm volatile("global_atomic_add %0, %1, off\n\t"
               "s_waitcnt vmcnt(0)"
               :: "v"(p), "v"(v) : "memory");
}
__device__ __forceinline__ unsigned xadd_ret0(unsigned* p) {
  unsigned r, z = 0u;
  asm volatile("global_atomic_add %0, %1, %2, off sc0\n\t"
               "s_waitcnt vmcnt(0)"
               : "=&v"(r) : "v"(p), "v"(z) : "memory");
  return r;
}

// Zero persistent state + precompute exp(efw). Stream-ordered each call ->
// deterministic per graph replay.
__global__ void lstm_init(const float* __restrict__ efw, float* __restrict__ ws) {
  int stride = gridDim.x * blockDim.x;
  for (int j = blockIdx.x * blockDim.x + threadIdx.x; j < OFF_ZEND; j += stride) {
    float v = 0.0f;
    if (j >= OFF_SCL && j < OFF_SCL + D_) v = expf(efw[j - OFF_SCL]);
    ws[j] = v;
  }
}

__launch_bounds__(NTHR, 1)
__global__ void lstm_persist(const float* __restrict__ x,
                             const float* __restrict__ W0,
                             const float* __restrict__ b0,
                             const float* __restrict__ W1,
                             const float* __restrict__ b1,
                             float* __restrict__ out,
                             float* __restrict__ ws,
                             const int stg)
{
  __shared__ float wW[K1][16];      // 64 KB   weight slice [k][col]
  __shared__ float aT[CK][68];      // 17 KB   A-chunk [k][row^swz]; XOR row bits
                                    // 2-4 with (k>>2)&7: write 2-way, read 2-way
                                    // (plain 68 write was 8-way: 1.7e9 cyc in R4)
  __shared__ float pR[4][B_][20];   // 20.5 KB per-wave partials
  __shared__ float scl[D_];         // 1 KB    exp(efw)
  __shared__ int   sslot;

  const int  wg  = blockIdx.x;
  const int  tid = threadIdx.x;
  const bool isA = (wg < NAH);
  const int  u0  = (isA ? wg : wg - NAH) * 4;
  const int  K   = isA ? K0 : K1;
  const int  nch = K / CK;          // 12 (A) / 16 (B)

  float* h0 = ws + OFF_H0;
  float* h1 = ws + OFF_H1;
  float* cs = ws + (isA ? OFF_C0 : OFF_C1);
  float* xbuf = ws + OFF_XBUF;
  unsigned* epo = (unsigned*)ws + OFF_EPO;
  unsigned* flg = (unsigned*)ws + OFF_FLG;
  unsigned* tkt = (unsigned*)ws + OFF_TKT;
  unsigned* xcnA = (unsigned*)ws + OFF_XCN;

  // One-time: stage weight slice into LDS (plain, read-only).
  {
    const float* W = isA ? W0 : W1;
    for (int i = tid; i < K * 16; i += NTHR) {
      int k = i >> 4, cl = i & 15, g = cl >> 2, u2 = cl & 3;
      wW[k][cl] = W[(size_t)k * G4 + g * H_ + u0 + u2];
    }
  }
  for (int i = tid; i < D_; i += NTHR) scl[i] = ws[OFF_SCL + i];

  // XCD identity + slot ticket (agent-scope RMW at IF$, one-time, R1-proven).
  int xcc = 0, slot = 0, nx = 1;
  if (stg) {
    // s_getreg hwreg(HW_REG_XCC_ID=20, off 0, sz 32): simm = (31<<11)|20
    xcc = (int)(__builtin_amdgcn_s_getreg(63508) & 7u);
    if (tid == 0)
      sslot = (int)__hip_atomic_fetch_add(tkt + (size_t)xcc * 16, 1u,
                                          __ATOMIC_RELAXED, __HIP_MEMORY_SCOPE_AGENT);
    __syncthreads();
    slot = sslot;
  }
  unsigned* xcnt = xcnA + (size_t)xcc * 16;

  // ---- global barrier (R4-proven sc1 flag protocol) ----
  auto gbar = [&](unsigned tgt) {
    __syncthreads();
    if (tid == 0) AST(flg + (size_t)wg * 16, tgt);
    if (wg == 0 && tid < 64) {
      for (;;) {
        unsigned m0 = ALD(flg + (size_t)(tid       ) * 16);
        unsigned m1 = ALD(flg + (size_t)(tid +  64) * 16);
        unsigned m2 = ALD(flg + (size_t)(tid + 128) * 16);
        unsigned m3 = ALD(flg + (size_t)(tid + 192) * 16);
        if (__all(m0 >= tgt && m1 >= tgt && m2 >= tgt && m3 >= tgt)) break;
      }
      if (tid == 0) {
#pragma unroll
        for (int kq = 0; kq < 8; ++kq) AST(epo + (size_t)kq * 16, tgt);
      }
    }
    if (tid < 64) {
      while (ALD(epo + (size_t)(wg & 7) * 16) < tgt)
        __builtin_amdgcn_s_sleep(4);
    }
    __syncthreads();
  };

  // ---- XCD-local barrier: one L2-point counter, +nx per event ----
  auto xbar = [&](unsigned ev) {
    __syncthreads();                  // vmcnt(0) drain: staging stores in L2
    if (tid == 0) {
      xadd_noret(xcnt, 1u);
      const unsigned tgt = ev * (unsigned)nx;
      while (xadd_ret0(xcnt) < tgt) __builtin_amdgcn_s_sleep(8);
    }
    __syncthreads();
  };

  // Pre-loop global barrier: tickets final + init zeros globally visible.
  gbar(1u);
  if (stg) nx = (int)ALD(tkt + (size_t)xcc * 16);   // residents on this XCD

  // Stager: copy {h0[q], h1[q]} (sc1, IF$-fresh) into this XCD's rot slot.
  // Slot-strided so any nx covers all 32 slices.
  auto stage_xcd = [&](int q, int rot) {
    for (int s = slot; s < 32; s += nx) {
      int off = s * 2048 + tid * 8;               // [0, 2*BH)
      const float* gs = (off < BH) ? ws + OFF_H0 + (size_t)q * BH + off
                                   : ws + OFF_H1 + (size_t)q * BH + (off - BH);
      float v0 = ALD(gs+0), v1 = ALD(gs+1), v2 = ALD(gs+2), v3 = ALD(gs+3);
      float v4 = ALD(gs+4), v5 = ALD(gs+5), v6 = ALD(gs+6), v7 = ALD(gs+7);
      float* dst = xbuf + ((size_t)xcc * NROT + rot) * (2 * BH) + off;
      float4 w0 = {v0,v1,v2,v3}, w1 = {v4,v5,v6,v7};
      *(float4*)(dst)     = w0;                   // plain: dirty in own L2
      *(float4*)(dst + 4) = w1;
    }
  };

  if (stg) {                // pre-stage parity 1 (zeros) into rot 3 (event 1)
    stage_xcd(1, 3);
    xbar(1u);
  }

  // GEMM-phase roles
  const int rq  = tid & 15;         // rows 4rq..4rq+3
  const int cq  = (tid >> 4) & 3;   // cols 4cq..4cq+3
  const int wv_ = tid >> 6;         // wave k-phase
  const int row_r = tid & 63;       // update-phase batch row
  const int uu    = tid >> 6;       // update-phase unit sub-index
  float bias[4];
  {
    const float* bv = isA ? b0 : b1;
#pragma unroll
    for (int g = 0; g < 4; ++g) bias[g] = bv[g * H_ + u0 + uu];
  }
  __syncthreads();

  const float *bh0 = nullptr, *bh1 = nullptr;  // per-round A-source bases

  float rg[16];
  auto stage_load = [&](int c, int t) {
    if (isA && c < 4) {                           // x part (plain, scaled)
#pragma unroll
      for (int i = 0; i < 4; ++i) {
        int s = tid + NTHR * i;
        int row = s >> 4, kk = (s & 15) << 2, gk = c * CK + kk;
        float4 v  = *(const float4*)(x + ((size_t)row * S_ + t) * D_ + gk);
        float4 sc = *(const float4*)&scl[gk];
        rg[4*i+0] = v.x * sc.x; rg[4*i+1] = v.y * sc.y;
        rg[4*i+2] = v.z * sc.z; rg[4*i+3] = v.w * sc.w;
      }
    } else {
      const float* base; int coloff;
      if (isA)         { base = bh0; coloff = c * CK - D_; }
      else if (c < 8)  { base = bh0; coloff = c * CK; }
      else             { base = bh1; coloff = c * CK - H_; }
      if (stg) {        // plain loads: L2-hit on staged lines; L0 staleness
                        // impossible (NROT=4 rotation > L0 lifetime)
#pragma unroll
        for (int i = 0; i < 4; ++i) {
          int s = tid + NTHR * i;
          int row = s >> 4, kk = (s & 15) << 2;
          float4 v = *(const float4*)(base + (size_t)row * H_ + coloff + kk);
          rg[4*i+0] = v.x; rg[4*i+1] = v.y; rg[4*i+2] = v.z; rg[4*i+3] = v.w;
        }
      } else {                                    // fallback: direct sc1 reads
#pragma unroll
        for (int i = 0; i < 4; ++i) {
          int s = tid + NTHR * i;
          int row = s >> 4, kk = (s & 15) << 2;
          const float* src = base + (size_t)row * H_ + coloff + kk;
          rg[4*i+0] = ALD(src+0); rg[4*i+1] = ALD(src+1);
          rg[4*i+2] = ALD(src+2); rg[4*i+3] = ALD(src+3);
        }
      }
    }
  };

  for (int r = 0; r <= S_; ++r) {
    const int  p   = r & 1;
    const bool act = isA ? (r < S_) : (r >= 1);
    if (act) {
      const int t = isA ? r : r - 1;
      if (stg) {        // consume the slot staged at end of round r-1
        const float* cb = xbuf + ((size_t)xcc * NROT + ((r + 3) & 3)) * (2 * BH);
        bh0 = cb; bh1 = cb + BH;
      } else {
        bh0 = h0 + (size_t)(p ^ 1) * BH; bh1 = h1 + (size_t)(p ^ 1) * BH;
      }
      float acc[4][4] = {{0.f,0.f,0.f,0.f},{0.f,0.f,0.f,0.f},
                         {0.f,0.f,0.f,0.f},{0.f,0.f,0.f,0.f}};
      stage_load(0, t);

      for (int c = 0; c < nch; ++c) {
        __syncthreads();
        // regs -> aT with row-XOR swizzle (row' = row ^ ((m&7)<<2), m = kk>>2)
#pragma unroll
        for (int i = 0; i < 4; ++i) {
          int s = tid + NTHR * i;
          int row = s >> 4, m = s & 15, kk = m << 2;
          int rw = row ^ ((m & 7) << 2);
          aT[kk+0][rw] = rg[4*i+0]; aT[kk+1][rw] = rg[4*i+1];
          aT[kk+2][rw] = rg[4*i+2]; aT[kk+3][rw] = rg[4*i+3];
        }
        if (c + 1 < nch) stage_load(c + 1, t);
        __syncthreads();
        const int kb = wv_ * 16;
#pragma unroll
        for (int kk = 0; kk < 16; ++kk) {
          const int kidx = kb + kk;
          float4 a  = *(const float4*)
              &aT[kidx][(rq << 2) ^ (((kidx >> 2) & 7) << 2)];
          float4 wv = *(const float4*)&wW[c * CK + kidx][cq << 2];
          acc[0][0] += a.x*wv.x; acc[0][1] += a.x*wv.y; acc[0][2] += a.x*wv.z; acc[0][3] += a.x*wv.w;
          acc[1][0] += a.y*wv.x; acc[1][1] += a.y*wv.y; acc[1][2] += a.y*wv.z; acc[1][3] += a.y*wv.w;
          acc[2][0] += a.z*wv.x; acc[2][1] += a.z*wv.y; acc[2][2] += a.z*wv.z; acc[2][3] += a.z*wv.w;
          acc[3][0] += a.w*wv.x; acc[3][1] += a.w*wv.y; acc[3][2] += a.w*wv.z; acc[3][3] += a.w*wv.w;
        }
      }

#pragma unroll
      for (int j = 0; j < 4; ++j) {
        pR[wv_][(rq<<2)+j][(cq<<2)+0] = acc[j][0];
        pR[wv_][(rq<<2)+j][(cq<<2)+1] = acc[j][1];
        pR[wv_][(rq<<2)+j][(cq<<2)+2] = acc[j][2];
        pR[wv_][(rq<<2)+j][(cq<<2)+3] = acc[j][3];
      }
      __syncthreads();

      float z[4];
#pragma unroll
      for (int g = 0; g < 4; ++g) {
        int cl = (g << 2) + uu;
        z[g] = pR[0][row_r][cl] + pR[1][row_r][cl]
             + pR[2][row_r][cl] + pR[3][row_r][cl] + bias[g];
      }
      const int ui = u0 + uu;
      float c_ = cs[(size_t)row_r * H_ + ui];
      float i_ = sigm(z[0]);
      float f_ = sigm(z[1] + c_) * 0.9f;          // decayed forget (DECAY=0.1)
      float g_ = tanhf(z[2]);
      float o_ = sigm(z[3]);
      float cn = f_ * c_ + i_ * g_;
      float hn = o_ * tanhf(cn);
      cs[(size_t)row_r * H_ + ui] = cn;
      float* hw = (isA ? h0 : h1) + (size_t)p * BH + (size_t)row_r * H_ + ui;
      AST(hw, hn);                                // sc1 write-through to IF$
      if (!isA) out[((size_t)row_r * S_ + t) * H_ + ui] = hn;
    }

    if (r < S_) {
      gbar((unsigned)(r + 2));                    // h[r] published at IF$
      if (stg) {                                  // localize h[r] into XCD L2
        stage_xcd(r & 1, r & 3);
        xbar((unsigned)(r + 2));
      }
    }
  }
}

extern "C" void kernel_launch(void* const* d_in, const int* in_sizes, int n_in,
                              void* d_out, int out_size, void* d_ws, size_t ws_size,
                              hipStream_t stream) {
  const float* x   = (const float*)d_in[0];
  const float* W0  = (const float*)d_in[1];
  const float* b0  = (const float*)d_in[2];
  const float* W1  = (const float*)d_in[3];
  const float* b1  = (const float*)d_in[4];
  const float* efw = (const float*)d_in[5];
  float* out = (float*)d_out;
  float* ws  = (float*)d_ws;

  if (ws_size < (size_t)OFF_ZEND * sizeof(float)) return;
  const int stg = (ws_size >= (size_t)OFF_END * sizeof(float)) ? 1 : 0;

  lstm_init<<<256, 256, 0, stream>>>(efw, ws);
  lstm_persist<<<NWG, NTHR, 0, stream>>>(x, W0, b0, W1, b1, out, ws, stg);
}